// Round 10
// baseline (82.164 us; speedup 1.0000x reference)
//
#include <hip/hip_runtime.h>
#include <hip/hip_fp16.h>

// Radon3D loss on MI355X — project the DIFFERENCE volume (radon is linear).
// Geometry (D=H=W=64, 120 angles over [0,120] deg): L=91, pad top=left=13.
//   ix(i,j) = 45*c*linj + 32 + 45*s - s*i,  iy(i,j) = 45*s*linj + 32 - 45*c + c*i
//   (unit steps in i: the 0.5*(L-1) unnormalization cancels the linspace step)
// WIDE 16-byte cells [D(y,x) 4-slice fp16 | D(y,x+1) 4-slice fp16] -> all 16
// bilinear corners from 2 x ds_read_b128 (rows y, y+1).
// NEW vs R7: XOR BANK SWIZZLE sw(i) = i ^ (((i>>3)^(i>>6)) & 7).
//   b128 bank-group = cell_index mod 8; lane stride Dci = round(69 sin + cos)
//   hits Dci % 8 == 0 for many of the 120 angles -> 8-way conflicts (the
//   ~2.5x gap between the 11 us LDS floor and the ~28 us measured kernel).
//   The swizzle varies the low 3 bits with higher bits -> lanes spread over
//   all 8 bank groups for every stride 8..64. Bijective, applied at write+read.
// Coords shifted +1 (nonneg), clamped to [0,65]: out-of-support samples hit
// the zero border with zero weight == map_coordinates mode='constant' cval=0.
#define DD 64
#define NA 120
#define LL 91
#define PS 67
#define PSTR 69               // cell stride per row
#define NCELL (PS * PSTR + 8) // +8 pad: swizzle can bump index up to |7
#define NSL 4                 // slices per block
#define NANG 8                // angles per block
#define JT 96                 // j-lanes per angle (91 active)
#define NTHR (NANG * JT)      // 768 threads = 12 waves
#define NSP (64 / NSL)        // 16 slice groups
#define NAP (NA / NANG)       // 15 angle groups
#define NBLKS (NSP * NAP)     // 240 blocks -> <=1 per CU, balanced

static __device__ __forceinline__ __half2 u2h(unsigned int u) {
    union { unsigned int u; __half2 h; } v; v.u = u; return v.h;
}
static __device__ __forceinline__ unsigned int h2u(__half2 h) {
    union { __half2 h; unsigned int u; } v; v.h = h; return v.u;
}
static __device__ __forceinline__ int sw(int i) {
    return i ^ (((i >> 3) ^ (i >> 6)) & 7);
}

__global__ __launch_bounds__(NTHR) void radon_loss_kernel(
    const float* __restrict__ vout, const float* __restrict__ vgt,
    float* __restrict__ out)
{
    __shared__ uint4 C[NCELL];           // wide swizzled canvas, 74.1 KB
    __shared__ float wsum[NTHR / 64];

    const int bid = blockIdx.x;
    const int sp = bid / NAP;            // slice group 0..15
    const int ap = bid - sp * NAP;       // angle group 0..14
    const int s0 = sp * NSL;
    const int t = threadIdx.x;

    // 1) zero the padded wide canvas (swizzle is a bijection; linear zeroing
    //    covers the same cells)
    for (int idx = t; idx < NCELL; idx += NTHR)
        C[idx] = make_uint4(0u, 0u, 0u, 0u);
    __syncthreads();

    // 2) stage fp16 diffs of 4 slices. Pixel (d,w) -> 8 B pack, written to
    //    cell(d+1, w+1).lo ("x" entry) and cell(d+1, w).hi ("x+1" entry).
    for (int idx = t; idx < DD * DD; idx += NTHR) {
        const int d = idx >> 6, w = idx & 63;
        const int g = d * 4096 + s0 * 64 + w;
        const float d0 = vout[g]       - vgt[g];
        const float d1 = vout[g + 64]  - vgt[g + 64];
        const float d2 = vout[g + 128] - vgt[g + 128];
        const float d3 = vout[g + 192] - vgt[g + 192];
        uint2 v8;
        v8.x = h2u(__floats2half2_rn(d0, d1));
        v8.y = h2u(__floats2half2_rn(d2, d3));
        const int rb = (d + 1) * PSTR + w;
        ((uint2*)&C[sw(rb + 1)])[0] = v8;    // D(y, x=w+1), lo half
        ((uint2*)&C[sw(rb)])[1]     = v8;    // D(y, x=w)'s x+1 entry, hi half
    }
    __syncthreads();

    // 3) projection: thread = (angle slot, column j); full i-range per thread
    const int ja = t / JT;
    const int j  = t - ja * JT;
    const int a  = ap * NANG + ja;
    const float theta = (float)a * (float)(3.14159265358979323846 * 120.0 / 119.0 / 180.0);
    const float c = cosf(theta), sn = sinf(theta);

    float val = 0.f;
    if (j < LL) {
        const float linj = fmaf((float)j, 2.0f / 90.0f, -1.0f);
        // +1 shift: coords in [0,65] after clamp; canvas row/col 0 is border
        const float bx1 = fmaf(c,  linj, 1.0f) * 45.0f - 12.0f + 45.0f * sn;
        const float by1 = fmaf(sn, linj, 1.0f) * 45.0f - 12.0f - 45.0f * c;
        __half2 acc01 = __floats2half2_rn(0.f, 0.f);
        __half2 acc23 = acc01;
        for (int i = 0; i < LL; ++i) {
            const float xs = fminf(fmaxf(fmaf(-(float)i, sn, bx1), 0.0f), 65.0f);
            const float ys = fminf(fmaxf(fmaf( (float)i, c,  by1), 0.0f), 65.0f);
            const int ix = (int)xs;            // trunc == floor (nonneg)
            const int iy = (int)ys;
            const float wx = xs - (float)ix;
            const float wy = ys - (float)iy;
            const __half2 wx2 = __float2half2_rn(wx);
            const __half2 wy2 = __float2half2_rn(wy);
            const int ci = iy * PSTR + ix;
            const uint4 q0 = C[sw(ci)];          // row y  : [D(x) | D(x+1)]
            const uint4 q1 = C[sw(ci + PSTR)];   // row y+1: [D(x) | D(x+1)]
            // slices 0,1
            const __half2 t01 = __hfma2(wx2, __hsub2(u2h(q0.z), u2h(q0.x)), u2h(q0.x));
            const __half2 b01 = __hfma2(wx2, __hsub2(u2h(q1.z), u2h(q1.x)), u2h(q1.x));
            acc01 = __hadd2(acc01, __hfma2(wy2, __hsub2(b01, t01), t01));
            // slices 2,3
            const __half2 t23 = __hfma2(wx2, __hsub2(u2h(q0.w), u2h(q0.y)), u2h(q0.y));
            const __half2 b23 = __hfma2(wx2, __hsub2(u2h(q1.w), u2h(q1.y)), u2h(q1.y));
            acc23 = __hadd2(acc23, __hfma2(wy2, __hsub2(b23, t23), t23));
        }
        const float2 a01 = __half22float2(acc01);
        const float2 a23 = __half22float2(acc23);
        val = fabsf(a01.x) + fabsf(a01.y) + fabsf(a23.x) + fabsf(a23.y);
    }

    // 4) block reduction + one scaled atomic per block
    #pragma unroll
    for (int off = 32; off > 0; off >>= 1)
        val += __shfl_down(val, off);
    const int wave = t >> 6, lane = t & 63;
    if (lane == 0) wsum[wave] = val;
    __syncthreads();
    if (t == 0) {
        float v = 0.f;
        #pragma unroll
        for (int wv = 0; wv < NTHR / 64; ++wv) v += wsum[wv];
        atomicAdd(out, v * (1.0f / (float)(NA * LL)));
    }
}

extern "C" void kernel_launch(void* const* d_in, const int* in_sizes, int n_in,
                              void* d_out, int out_size, void* d_ws, size_t ws_size,
                              hipStream_t stream) {
    const float* vout = (const float*)d_in[0];
    const float* vgt  = (const float*)d_in[1];
    float* out = (float*)d_out;

    hipMemsetAsync(out, 0, sizeof(float), stream);
    radon_loss_kernel<<<NBLKS, NTHR, 0, stream>>>(vout, vgt, out);
}